// Round 3
// baseline (373.540 us; speedup 1.0000x reference)
//
#include <hip/hip_runtime.h>
#include <math.h>

#define B_   32
#define C_   1024
#define N_   784
#define NF4  196          // N_/4 float4 per row
#define TD   768
#define AD   256
#define RED_ 64
#define OUT0 25690112     // B*C*H*W
#define ROWS (B_*C_)      // 32768
#define SCH  64           // score chunks (16 channels each) -> 2048 blocks

// workspace layout (float offsets)
#define OFF_AVG  0
#define OFF_MAX  32768
#define OFF_CA   65536
#define OFF_Q    98304    // B*AD = 8192
#define OFF_HS   106496   // B*RED = 2048
#define OFF_G    108544   // 32768
#define OFF_WVO  141312   // 1024
#define OFF_ATTN 142336   // B*N = 25088
#define OFF_SDOT 167424   // 32
#define OFF_PART 167456   // B*SCH*N = 1605632 -> end ~1.77M floats (~6.8 MB)

// ---------------- K1: per-row avg & max (1 wave per (b,c) row) ----------------
__global__ void k_avgmax(const float* __restrict__ x, float* __restrict__ avg,
                         float* __restrict__ mx) {
    int row  = blockIdx.x * 4 + (threadIdx.x >> 6);
    int lane = threadIdx.x & 63;
    const float4* xr = (const float4*)(x + (size_t)row * N_);
    float s = 0.f, m = -3.4e38f;
    for (int i = lane; i < NF4; i += 64) {
        float4 v = xr[i];
        s += v.x + v.y + v.z + v.w;
        m = fmaxf(m, fmaxf(fmaxf(v.x, v.y), fmaxf(v.z, v.w)));
    }
    for (int o = 32; o; o >>= 1) {
        s += __shfl_down(s, o, 64);
        m = fmaxf(m, __shfl_down(m, o, 64));
    }
    if (lane == 0) { avg[row] = s * (1.f / (float)N_); mx[row] = m; }
}

// ---------------- K2 (merged): q, hs, wvo via blockIdx branch ----------------
__global__ void k_proj(const float* __restrict__ text, const float* __restrict__ wq,
                       const float* __restrict__ avg, const float* __restrict__ mx,
                       const float* __restrict__ w1, const float* __restrict__ wv,
                       const float* __restrict__ wo, float* __restrict__ q,
                       float* __restrict__ hs, float* __restrict__ wvo) {
    int blk  = blockIdx.x;
    int wave = threadIdx.x >> 6, lane = threadIdx.x & 63;
    if (blk < 2048) {
        // q[b][a] = dot(text[b], wq[a]) — wave per output
        int w = blk * 4 + wave;           // 0..8191
        int b = w >> 8, a = w & 255;
        const float4* tb = (const float4*)(text + (size_t)b * TD);   // 192 f4
        const float4* wr = (const float4*)(wq + (size_t)a * TD);
        float acc = 0.f;
        #pragma unroll
        for (int j = 0; j < 3; ++j) {
            int i = lane + 64 * j;
            float4 tv = tb[i], wvv = wr[i];
            acc += tv.x * wvv.x + tv.y * wvv.y + tv.z * wvv.z + tv.w * wvv.w;
        }
        for (int o = 32; o; o >>= 1) acc += __shfl_down(acc, o, 64);
        if (lane == 0) q[(size_t)b * AD + a] = acc;
    } else if (blk < 2560) {
        // hs[b][r] = relu(avg.w1r) + relu(max.w1r) — wave per output
        int w = (blk - 2048) * 4 + wave;  // 0..2047
        int b = w >> 6, r = w & 63;
        const float4* av = (const float4*)(avg + (size_t)b * C_);    // 256 f4
        const float4* mv = (const float4*)(mx + (size_t)b * C_);
        const float4* wr = (const float4*)(w1 + (size_t)r * C_);
        float aa = 0.f, am = 0.f;
        #pragma unroll
        for (int j = 0; j < 4; ++j) {
            int i = lane + 64 * j;
            float4 wvv = wr[i], a4 = av[i], m4 = mv[i];
            aa += wvv.x * a4.x + wvv.y * a4.y + wvv.z * a4.z + wvv.w * a4.w;
            am += wvv.x * m4.x + wvv.y * m4.y + wvv.z * m4.z + wvv.w * m4.w;
        }
        for (int o = 32; o; o >>= 1) {
            aa += __shfl_down(aa, o, 64);
            am += __shfl_down(am, o, 64);
        }
        if (lane == 0) hs[(size_t)b * RED_ + r] = fmaxf(aa, 0.f) + fmaxf(am, 0.f);
    } else {
        // wvo[c] = sum_a wo[a]*wv[a][c]
        int c = (blk - 2560) * 256 + threadIdx.x;
        float acc = 0.f;
        for (int a = 0; a < AD; ++a) acc += wo[a] * wv[(size_t)a * C_ + c];
        wvo[c] = acc;
    }
}

// ---------------- K3 (merged): ca + g, thread per (b,c) ----------------------
__global__ void k_cag(const float* __restrict__ hs, const float* __restrict__ w2,
                      const float* __restrict__ q, const float* __restrict__ wk,
                      float* __restrict__ ca, float* __restrict__ g) {
    int b = blockIdx.y;
    int t = threadIdx.x;
    int c = blockIdx.x * 256 + t;
    __shared__ float qs[AD];
    __shared__ float hss[RED_];
    qs[t] = q[(size_t)b * AD + t];
    if (t < RED_) hss[t] = hs[(size_t)b * RED_ + t];
    __syncthreads();
    float a1 = 0.f;
    #pragma unroll
    for (int r = 0; r < RED_; ++r) a1 += hss[r] * w2[(size_t)c * RED_ + r];
    float cav = 1.f / (1.f + __expf(-a1));
    ca[(size_t)b * C_ + c] = cav;
    float a2 = 0.f;
    #pragma unroll 8
    for (int a = 0; a < AD; ++a) a2 += qs[a] * wk[(size_t)a * C_ + c];
    g[(size_t)b * C_ + c] = a2 * cav * 0.0625f;
}

// ---------------- K4: scores partials, 16 channels/block, float4 -------------
__global__ void k_scores(const float* __restrict__ x, const float* __restrict__ g,
                         float* __restrict__ part) {
    int chunk = blockIdx.x;   // 0..63 (16 channels each)
    int b     = blockIdx.y;
    int t     = threadIdx.x;
    int wave  = t >> 6, lane = t & 63;
    __shared__ float gs[16];
    __shared__ float4 l4[4 * NF4];
    if (t < 16) gs[t] = g[(size_t)b * C_ + chunk * 16 + t];
    __syncthreads();
    const float4* xb4 = (const float4*)(x +
        ((size_t)b * C_ + (size_t)chunk * 16 + (size_t)wave * 4) * N_);
    float4 a0 = {0,0,0,0}, a1 = {0,0,0,0}, a2 = {0,0,0,0}, a3 = {0,0,0,0};
    #pragma unroll
    for (int c = 0; c < 4; ++c) {
        float gv = gs[wave * 4 + c];
        const float4* row = xb4 + (size_t)c * NF4;
        float4 v;
        v = row[lane];       a0.x += gv*v.x; a0.y += gv*v.y; a0.z += gv*v.z; a0.w += gv*v.w;
        v = row[lane + 64];  a1.x += gv*v.x; a1.y += gv*v.y; a1.z += gv*v.z; a1.w += gv*v.w;
        v = row[lane + 128]; a2.x += gv*v.x; a2.y += gv*v.y; a2.z += gv*v.z; a2.w += gv*v.w;
        if (lane < 4) {
            v = row[lane + 192]; a3.x += gv*v.x; a3.y += gv*v.y; a3.z += gv*v.z; a3.w += gv*v.w;
        }
    }
    l4[wave * NF4 + lane]       = a0;
    l4[wave * NF4 + lane + 64]  = a1;
    l4[wave * NF4 + lane + 128] = a2;
    if (lane < 4) l4[wave * NF4 + lane + 192] = a3;
    __syncthreads();
    if (t < NF4) {
        float4 s0 = l4[t], s1 = l4[NF4 + t], s2 = l4[2 * NF4 + t], s3 = l4[3 * NF4 + t];
        float4 r;
        r.x = s0.x + s1.x + s2.x + s3.x;
        r.y = s0.y + s1.y + s2.y + s3.y;
        r.z = s0.z + s1.z + s2.z + s3.z;
        r.w = s0.w + s1.w + s2.w + s3.w;
        ((float4*)(part + ((size_t)b * SCH + chunk) * N_))[t] = r;
    }
}

// ---------------- K5: reduce partials + softmax -> attn; zero sdot -----------
__global__ void k_softmax(const float* __restrict__ part, float* __restrict__ attn,
                          float* __restrict__ sdot) {
    int b = blockIdx.x;
    int t = threadIdx.x;
    int lane = t & 63, wave = t >> 6;
    if (t == 0) sdot[b] = 0.f;
    const float* p = part + (size_t)b * SCH * N_;
    float v0 = 0.f, v1 = 0.f, v2 = 0.f, v3 = 0.f;
    for (int ch = 0; ch < SCH; ++ch) {
        const float* pc = p + (size_t)ch * N_;
        v0 += pc[t]; v1 += pc[t + 256]; v2 += pc[t + 512];
        if (t < 16) v3 += pc[t + 768];
    }
    float m = fmaxf(fmaxf(v0, v1), v2);
    if (t < 16) m = fmaxf(m, v3);
    for (int o = 32; o; o >>= 1) m = fmaxf(m, __shfl_down(m, o, 64));
    __shared__ float rm[4], rs[4];
    if (lane == 0) rm[wave] = m;
    __syncthreads();
    float M = fmaxf(fmaxf(rm[0], rm[1]), fmaxf(rm[2], rm[3]));
    float e0 = __expf(v0 - M), e1 = __expf(v1 - M), e2 = __expf(v2 - M);
    float e3 = (t < 16) ? __expf(v3 - M) : 0.f;
    float ssum = e0 + e1 + e2 + e3;
    for (int o = 32; o; o >>= 1) ssum += __shfl_down(ssum, o, 64);
    if (lane == 0) rs[wave] = ssum;
    __syncthreads();
    float inv = 1.f / (rs[0] + rs[1] + rs[2] + rs[3]);
    float* ab = attn + (size_t)b * N_;
    ab[t] = e0 * inv; ab[t + 256] = e1 * inv; ab[t + 512] = e2 * inv;
    if (t < 16) ab[t + 768] = e3 * inv;
}

// ---------------- K6: attend + fold scalar dot via 1 atomic per block --------
__global__ void k_attend(const float* __restrict__ x, const float* __restrict__ attn,
                         const float* __restrict__ chattn, const float* __restrict__ wvo,
                         float* __restrict__ sdot) {
    int wave = threadIdx.x >> 6, lane = threadIdx.x & 63;
    int row  = blockIdx.x * 4 + wave;
    int b    = row >> 10, c = row & 1023;
    const float4* xr = (const float4*)(x + (size_t)row * N_);
    const float4* ar = (const float4*)(attn + (size_t)b * N_);
    float s = 0.f;
    #pragma unroll
    for (int j = 0; j < 3; ++j) {
        int i = lane + 64 * j;
        float4 xv = xr[i], av = ar[i];
        s += xv.x * av.x + xv.y * av.y + xv.z * av.z + xv.w * av.w;
    }
    if (lane < 4) {
        float4 xv = xr[lane + 192], av = ar[lane + 192];
        s += xv.x * av.x + xv.y * av.y + xv.z * av.z + xv.w * av.w;
    }
    for (int o = 32; o; o >>= 1) s += __shfl_down(s, o, 64);
    __shared__ float wsum[4];
    if (lane == 0) wsum[wave] = s * chattn[row] * wvo[c];
    __syncthreads();
    if (threadIdx.x == 0)
        atomicAdd(&sdot[b], wsum[0] + wsum[1] + wsum[2] + wsum[3]);
}

// ---------------- K7: out0 = x*ca*sigmoid(sdot) ; out1 = broadcast -----------
__global__ void k_finalize(const float* __restrict__ x, const float* __restrict__ chattn,
                           const float* __restrict__ sdot, float* __restrict__ out) {
    int blk = blockIdx.x;
    if (blk < ROWS / 4) {
        int row  = blk * 4 + (threadIdx.x >> 6);
        int lane = threadIdx.x & 63;
        int b    = row >> 10;
        float sb = 1.f / (1.f + __expf(-sdot[b]));
        float sc = chattn[row] * sb;
        const float4* xr = (const float4*)(x + (size_t)row * N_);
        float4* orow = (float4*)(out + (size_t)row * N_);
        for (int i = lane; i < NF4; i += 64) {
            float4 v = xr[i];
            v.x *= sc; v.y *= sc; v.z *= sc; v.w *= sc;
            orow[i] = v;
        }
    } else {
        int idx = (blk - ROWS / 4) * 256 + threadIdx.x;  // float4 index into out1
        if (idx < (B_ * N_) / 4) {
            int b = idx / (N_ / 4);
            float v = 1.f / (1.f + __expf(-sdot[b]));
            ((float4*)(out + OUT0))[idx] = make_float4(v, v, v, v);
        }
    }
}

extern "C" void kernel_launch(void* const* d_in, const int* in_sizes, int n_in,
                              void* d_out, int out_size, void* d_ws, size_t ws_size,
                              hipStream_t stream) {
    const float* x    = (const float*)d_in[0];
    const float* text = (const float*)d_in[1];
    const float* w1   = (const float*)d_in[2];
    const float* w2   = (const float*)d_in[3];
    const float* wq   = (const float*)d_in[4];
    const float* wk   = (const float*)d_in[5];
    const float* wv   = (const float*)d_in[6];
    const float* wo   = (const float*)d_in[7];
    float* out = (float*)d_out;
    float* ws  = (float*)d_ws;

    float* avg  = ws + OFF_AVG;
    float* mx   = ws + OFF_MAX;
    float* ca   = ws + OFF_CA;
    float* q    = ws + OFF_Q;
    float* hs   = ws + OFF_HS;
    float* g    = ws + OFF_G;
    float* wvo  = ws + OFF_WVO;
    float* attn = ws + OFF_ATTN;
    float* sdot = ws + OFF_SDOT;
    float* part = ws + OFF_PART;

    k_avgmax<<<ROWS / 4, 256, 0, stream>>>(x, avg, mx);
    k_proj<<<2564, 256, 0, stream>>>(text, wq, avg, mx, w1, wv, wo, q, hs, wvo);
    k_cag<<<dim3(C_ / 256, B_), 256, 0, stream>>>(hs, w2, q, wk, ca, g);
    k_scores<<<dim3(SCH, B_), 256, 0, stream>>>(x, g, part);
    k_softmax<<<B_, 256, 0, stream>>>(part, attn, sdot);
    k_attend<<<ROWS / 4, 256, 0, stream>>>(x, attn, ca, wvo, sdot);
    k_finalize<<<ROWS / 4 + 25, 256, 0, stream>>>(x, ca, sdot, out);
}

// Round 4
// 297.010 us; speedup vs baseline: 1.2577x; 1.2577x over previous
//
#include <hip/hip_runtime.h>
#include <math.h>

#define B_   32
#define C_   1024
#define N_   784
#define NF4  196          // N_/4 float4 per row
#define TD   768
#define AD   256
#define RED_ 64
#define OUT0 25690112     // B*C*H*W
#define ROWS (B_*C_)      // 32768
#define SCH  64           // score chunks (16 channels each) -> 2048 blocks

// workspace layout (float offsets)
#define OFF_AVG  0
#define OFF_MAX  32768
#define OFF_CA   65536
#define OFF_Q    98304    // B*AD = 8192
#define OFF_HS   106496   // B*RED = 2048
#define OFF_G    108544   // 32768
#define OFF_WVO  141312   // 1024
#define OFF_ATTN 142336   // B*N = 25088
#define OFF_T    167424   // 32768
#define OFF_S    200192   // 32
#define OFF_PART 200224   // B*SCH*N = 1605632 -> ~6.9 MB total

// ---------------- K1: per-row avg & max (2 rows per wave, ILP) ---------------
__global__ void k_avgmax(const float* __restrict__ x, float* __restrict__ avg,
                         float* __restrict__ mx) {
    int wave = threadIdx.x >> 6, lane = threadIdx.x & 63;
    int row0 = blockIdx.x * 8 + wave * 2;
    const float4* r0 = (const float4*)(x + (size_t)row0 * N_);
    const float4* r1 = r0 + NF4;
    float s0 = 0.f, s1 = 0.f, m0 = -3.4e38f, m1 = -3.4e38f;
    #pragma unroll
    for (int j = 0; j < 3; ++j) {
        int i = lane + 64 * j;
        float4 v0 = r0[i], v1 = r1[i];
        s0 += v0.x + v0.y + v0.z + v0.w;
        s1 += v1.x + v1.y + v1.z + v1.w;
        m0 = fmaxf(m0, fmaxf(fmaxf(v0.x, v0.y), fmaxf(v0.z, v0.w)));
        m1 = fmaxf(m1, fmaxf(fmaxf(v1.x, v1.y), fmaxf(v1.z, v1.w)));
    }
    if (lane < 4) {
        float4 v0 = r0[192 + lane], v1 = r1[192 + lane];
        s0 += v0.x + v0.y + v0.z + v0.w;
        s1 += v1.x + v1.y + v1.z + v1.w;
        m0 = fmaxf(m0, fmaxf(fmaxf(v0.x, v0.y), fmaxf(v0.z, v0.w)));
        m1 = fmaxf(m1, fmaxf(fmaxf(v1.x, v1.y), fmaxf(v1.z, v1.w)));
    }
    for (int o = 32; o; o >>= 1) {
        s0 += __shfl_down(s0, o, 64);
        s1 += __shfl_down(s1, o, 64);
        m0 = fmaxf(m0, __shfl_down(m0, o, 64));
        m1 = fmaxf(m1, __shfl_down(m1, o, 64));
    }
    if (lane == 0) {
        avg[row0]     = s0 * (1.f / (float)N_); mx[row0]     = m0;
        avg[row0 + 1] = s1 * (1.f / (float)N_); mx[row0 + 1] = m1;
    }
}

// ---------------- K2 (merged): q, hs, wvo via blockIdx branch ----------------
__global__ void k_proj(const float* __restrict__ text, const float* __restrict__ wq,
                       const float* __restrict__ avg, const float* __restrict__ mx,
                       const float* __restrict__ w1, const float* __restrict__ wv,
                       const float* __restrict__ wo, float* __restrict__ q,
                       float* __restrict__ hs, float* __restrict__ wvo) {
    int blk  = blockIdx.x;
    int wave = threadIdx.x >> 6, lane = threadIdx.x & 63;
    if (blk < 2048) {
        int w = blk * 4 + wave;           // 0..8191
        int b = w >> 8, a = w & 255;
        const float4* tb = (const float4*)(text + (size_t)b * TD);   // 192 f4
        const float4* wr = (const float4*)(wq + (size_t)a * TD);
        float acc = 0.f;
        #pragma unroll
        for (int j = 0; j < 3; ++j) {
            int i = lane + 64 * j;
            float4 tv = tb[i], wvv = wr[i];
            acc += tv.x * wvv.x + tv.y * wvv.y + tv.z * wvv.z + tv.w * wvv.w;
        }
        for (int o = 32; o; o >>= 1) acc += __shfl_down(acc, o, 64);
        if (lane == 0) q[(size_t)b * AD + a] = acc;
    } else if (blk < 2560) {
        int w = (blk - 2048) * 4 + wave;  // 0..2047
        int b = w >> 6, r = w & 63;
        const float4* av = (const float4*)(avg + (size_t)b * C_);    // 256 f4
        const float4* mv = (const float4*)(mx + (size_t)b * C_);
        const float4* wr = (const float4*)(w1 + (size_t)r * C_);
        float aa = 0.f, am = 0.f;
        #pragma unroll
        for (int j = 0; j < 4; ++j) {
            int i = lane + 64 * j;
            float4 wvv = wr[i], a4 = av[i], m4 = mv[i];
            aa += wvv.x * a4.x + wvv.y * a4.y + wvv.z * a4.z + wvv.w * a4.w;
            am += wvv.x * m4.x + wvv.y * m4.y + wvv.z * m4.z + wvv.w * m4.w;
        }
        for (int o = 32; o; o >>= 1) {
            aa += __shfl_down(aa, o, 64);
            am += __shfl_down(am, o, 64);
        }
        if (lane == 0) hs[(size_t)b * RED_ + r] = fmaxf(aa, 0.f) + fmaxf(am, 0.f);
    } else {
        int c = (blk - 2560) * 256 + threadIdx.x;
        float acc = 0.f;
        for (int a = 0; a < AD; ++a) acc += wo[a] * wv[(size_t)a * C_ + c];
        wvo[c] = acc;
    }
}

// ---------------- K3 (merged): ca + g, thread per (b,c) ----------------------
__global__ void k_cag(const float* __restrict__ hs, const float* __restrict__ w2,
                      const float* __restrict__ q, const float* __restrict__ wk,
                      float* __restrict__ ca, float* __restrict__ g) {
    int b = blockIdx.y;
    int t = threadIdx.x;
    int c = blockIdx.x * 256 + t;
    __shared__ float qs[AD];
    __shared__ float hss[RED_];
    qs[t] = q[(size_t)b * AD + t];
    if (t < RED_) hss[t] = hs[(size_t)b * RED_ + t];
    __syncthreads();
    float a1 = 0.f;
    #pragma unroll
    for (int r = 0; r < RED_; ++r) a1 += hss[r] * w2[(size_t)c * RED_ + r];
    float cav = 1.f / (1.f + __expf(-a1));
    ca[(size_t)b * C_ + c] = cav;
    float a2 = 0.f;
    #pragma unroll 8
    for (int a = 0; a < AD; ++a) a2 += qs[a] * wk[(size_t)a * C_ + c];
    g[(size_t)b * C_ + c] = a2 * cav * 0.0625f;
}

// ---------------- K4: scores partials, 16 channels/block, float4 -------------
__global__ void k_scores(const float* __restrict__ x, const float* __restrict__ g,
                         float* __restrict__ part) {
    int chunk = blockIdx.x;   // 0..63 (16 channels each)
    int b     = blockIdx.y;
    int t     = threadIdx.x;
    int wave  = t >> 6, lane = t & 63;
    __shared__ float gs[16];
    __shared__ float4 l4[4 * NF4];
    if (t < 16) gs[t] = g[(size_t)b * C_ + chunk * 16 + t];
    __syncthreads();
    const float4* xb4 = (const float4*)(x +
        ((size_t)b * C_ + (size_t)chunk * 16 + (size_t)wave * 4) * N_);
    float4 a0 = {0,0,0,0}, a1 = {0,0,0,0}, a2 = {0,0,0,0}, a3 = {0,0,0,0};
    #pragma unroll
    for (int c = 0; c < 4; ++c) {
        float gv = gs[wave * 4 + c];
        const float4* row = xb4 + (size_t)c * NF4;
        float4 v;
        v = row[lane];       a0.x += gv*v.x; a0.y += gv*v.y; a0.z += gv*v.z; a0.w += gv*v.w;
        v = row[lane + 64];  a1.x += gv*v.x; a1.y += gv*v.y; a1.z += gv*v.z; a1.w += gv*v.w;
        v = row[lane + 128]; a2.x += gv*v.x; a2.y += gv*v.y; a2.z += gv*v.z; a2.w += gv*v.w;
        if (lane < 4) {
            v = row[lane + 192]; a3.x += gv*v.x; a3.y += gv*v.y; a3.z += gv*v.z; a3.w += gv*v.w;
        }
    }
    l4[wave * NF4 + lane]       = a0;
    l4[wave * NF4 + lane + 64]  = a1;
    l4[wave * NF4 + lane + 128] = a2;
    if (lane < 4) l4[wave * NF4 + lane + 192] = a3;
    __syncthreads();
    if (t < NF4) {
        float4 s0 = l4[t], s1 = l4[NF4 + t], s2 = l4[2 * NF4 + t], s3 = l4[3 * NF4 + t];
        float4 r;
        r.x = s0.x + s1.x + s2.x + s3.x;
        r.y = s0.y + s1.y + s2.y + s3.y;
        r.z = s0.z + s1.z + s2.z + s3.z;
        r.w = s0.w + s1.w + s2.w + s3.w;
        ((float4*)(part + ((size_t)b * SCH + chunk) * N_))[t] = r;
    }
}

// ---------------- K5: reduce partials + softmax -> attn ----------------------
__global__ void k_softmax(const float* __restrict__ part, float* __restrict__ attn) {
    int b = blockIdx.x;
    int t = threadIdx.x;
    int lane = t & 63, wave = t >> 6;
    const float* p = part + (size_t)b * SCH * N_;
    float v0 = 0.f, v1 = 0.f, v2 = 0.f, v3 = 0.f;
    for (int ch = 0; ch < SCH; ++ch) {
        const float* pc = p + (size_t)ch * N_;
        v0 += pc[t]; v1 += pc[t + 256]; v2 += pc[t + 512];
        if (t < 16) v3 += pc[t + 768];
    }
    float m = fmaxf(fmaxf(v0, v1), v2);
    if (t < 16) m = fmaxf(m, v3);
    for (int o = 32; o; o >>= 1) m = fmaxf(m, __shfl_down(m, o, 64));
    __shared__ float rm[4], rs[4];
    if (lane == 0) rm[wave] = m;
    __syncthreads();
    float M = fmaxf(fmaxf(rm[0], rm[1]), fmaxf(rm[2], rm[3]));
    float e0 = __expf(v0 - M), e1 = __expf(v1 - M), e2 = __expf(v2 - M);
    float e3 = (t < 16) ? __expf(v3 - M) : 0.f;
    float ssum = e0 + e1 + e2 + e3;
    for (int o = 32; o; o >>= 1) ssum += __shfl_down(ssum, o, 64);
    if (lane == 0) rs[wave] = ssum;
    __syncthreads();
    float inv = 1.f / (rs[0] + rs[1] + rs[2] + rs[3]);
    float* ab = attn + (size_t)b * N_;
    ab[t] = e0 * inv; ab[t + 256] = e1 * inv; ab[t + 512] = e2 * inv;
    if (t < 16) ab[t + 768] = e3 * inv;
}

// ---------------- K6: attend, 2 rows per wave, t_out includes ca*wvo ---------
__global__ void k_attend(const float* __restrict__ x, const float* __restrict__ attn,
                         const float* __restrict__ chattn, const float* __restrict__ wvo,
                         float* __restrict__ t_out) {
    int wave = threadIdx.x >> 6, lane = threadIdx.x & 63;
    int row0 = blockIdx.x * 8 + wave * 2;
    int b    = row0 >> 10;
    const float4* r0 = (const float4*)(x + (size_t)row0 * N_);
    const float4* r1 = r0 + NF4;
    const float4* ar = (const float4*)(attn + (size_t)b * N_);
    float s0 = 0.f, s1 = 0.f;
    #pragma unroll
    for (int j = 0; j < 3; ++j) {
        int i = lane + 64 * j;
        float4 av = ar[i];
        float4 v0 = r0[i], v1 = r1[i];
        s0 += v0.x * av.x + v0.y * av.y + v0.z * av.z + v0.w * av.w;
        s1 += v1.x * av.x + v1.y * av.y + v1.z * av.z + v1.w * av.w;
    }
    if (lane < 4) {
        float4 av = ar[192 + lane];
        float4 v0 = r0[192 + lane], v1 = r1[192 + lane];
        s0 += v0.x * av.x + v0.y * av.y + v0.z * av.z + v0.w * av.w;
        s1 += v1.x * av.x + v1.y * av.y + v1.z * av.z + v1.w * av.w;
    }
    for (int o = 32; o; o >>= 1) {
        s0 += __shfl_down(s0, o, 64);
        s1 += __shfl_down(s1, o, 64);
    }
    if (lane == 0) {
        int c0 = row0 & 1023;
        t_out[row0]     = s0 * chattn[row0]     * wvo[c0];
        t_out[row0 + 1] = s1 * chattn[row0 + 1] * wvo[c0 + 1];
    }
}

// ---------------- K7: sv[b] = sigmoid(sum_c t[b][c])  (wave per b) -----------
__global__ void k_scalar(const float* __restrict__ t_in, float* __restrict__ s_out) {
    int b    = blockIdx.x * 4 + (threadIdx.x >> 6);   // 0..31
    int lane = threadIdx.x & 63;
    const float4* tb = (const float4*)(t_in + (size_t)b * C_);   // 256 f4
    float acc = 0.f;
    #pragma unroll
    for (int j = 0; j < 4; ++j) {
        float4 tv = tb[lane + 64 * j];
        acc += tv.x + tv.y + tv.z + tv.w;
    }
    for (int o = 32; o; o >>= 1) acc += __shfl_down(acc, o, 64);
    if (lane == 0) s_out[b] = 1.f / (1.f + __expf(-acc));
}

// ---------------- K8: out0 = x*ca*s (2 rows/wave) ; out1 = broadcast ---------
__global__ void k_finalize(const float* __restrict__ x, const float* __restrict__ chattn,
                           const float* __restrict__ s, float* __restrict__ out) {
    int blk = blockIdx.x;
    if (blk < ROWS / 8) {
        int wave = threadIdx.x >> 6, lane = threadIdx.x & 63;
        int row0 = blk * 8 + wave * 2;
        int b    = row0 >> 10;
        float sb  = s[b];
        float sc0 = chattn[row0] * sb;
        float sc1 = chattn[row0 + 1] * sb;
        const float4* r0 = (const float4*)(x + (size_t)row0 * N_);
        const float4* r1 = r0 + NF4;
        float4* o0 = (float4*)(out + (size_t)row0 * N_);
        float4* o1 = o0 + NF4;
        #pragma unroll
        for (int j = 0; j < 3; ++j) {
            int i = lane + 64 * j;
            float4 v0 = r0[i], v1 = r1[i];
            v0.x *= sc0; v0.y *= sc0; v0.z *= sc0; v0.w *= sc0;
            v1.x *= sc1; v1.y *= sc1; v1.z *= sc1; v1.w *= sc1;
            o0[i] = v0; o1[i] = v1;
        }
        if (lane < 4) {
            int i = 192 + lane;
            float4 v0 = r0[i], v1 = r1[i];
            v0.x *= sc0; v0.y *= sc0; v0.z *= sc0; v0.w *= sc0;
            v1.x *= sc1; v1.y *= sc1; v1.z *= sc1; v1.w *= sc1;
            o0[i] = v0; o1[i] = v1;
        }
    } else {
        int idx = (blk - ROWS / 8) * 256 + threadIdx.x;  // float4 index into out1
        if (idx < (B_ * N_) / 4) {
            int b = idx / (N_ / 4);
            float v = s[b];
            ((float4*)(out + OUT0))[idx] = make_float4(v, v, v, v);
        }
    }
}

extern "C" void kernel_launch(void* const* d_in, const int* in_sizes, int n_in,
                              void* d_out, int out_size, void* d_ws, size_t ws_size,
                              hipStream_t stream) {
    const float* x    = (const float*)d_in[0];
    const float* text = (const float*)d_in[1];
    const float* w1   = (const float*)d_in[2];
    const float* w2   = (const float*)d_in[3];
    const float* wq   = (const float*)d_in[4];
    const float* wk   = (const float*)d_in[5];
    const float* wv   = (const float*)d_in[6];
    const float* wo   = (const float*)d_in[7];
    float* out = (float*)d_out;
    float* ws  = (float*)d_ws;

    float* avg  = ws + OFF_AVG;
    float* mx   = ws + OFF_MAX;
    float* ca   = ws + OFF_CA;
    float* q    = ws + OFF_Q;
    float* hs   = ws + OFF_HS;
    float* g    = ws + OFF_G;
    float* wvo  = ws + OFF_WVO;
    float* attn = ws + OFF_ATTN;
    float* tt   = ws + OFF_T;
    float* sv   = ws + OFF_S;
    float* part = ws + OFF_PART;

    k_avgmax<<<ROWS / 8, 256, 0, stream>>>(x, avg, mx);
    k_proj<<<2564, 256, 0, stream>>>(text, wq, avg, mx, w1, wv, wo, q, hs, wvo);
    k_cag<<<dim3(C_ / 256, B_), 256, 0, stream>>>(hs, w2, q, wk, ca, g);
    k_scores<<<dim3(SCH, B_), 256, 0, stream>>>(x, g, part);
    k_softmax<<<B_, 256, 0, stream>>>(part, attn);
    k_attend<<<ROWS / 8, 256, 0, stream>>>(x, attn, ca, wvo, tt);
    k_scalar<<<B_ / 4, 256, 0, stream>>>(tt, sv);
    k_finalize<<<ROWS / 8 + 25, 256, 0, stream>>>(x, ca, sv, out);
}